// Round 1
// baseline (1454.533 us; speedup 1.0000x reference)
//
#include <hip/hip_runtime.h>
#include <hip/hip_bf16.h>

#define N_ATOMS   32768
#define N_SPECIES 4
#define N_FEAT    7584
#define HIDDEN    256
#define N_STRUCT  1024
#define APS       8192   // atoms per species

typedef __attribute__((ext_vector_type(8))) short bf16x8;
typedef __attribute__((ext_vector_type(4))) float f32x4;

typedef const __attribute__((address_space(1))) void* gptr_t;
typedef __attribute__((address_space(3))) void* lptr_t;

__device__ __forceinline__ unsigned short f2bf(float x) {
    union { float f; unsigned u; } v; v.f = x;
    unsigned r = v.u + 0x7FFFu + ((v.u >> 16) & 1u);   // RNE
    return (unsigned short)(r >> 16);
}
__device__ __forceinline__ float bf2f(unsigned short h) {
    union { unsigned u; float f; } v; v.u = ((unsigned)h) << 16;
    return v.f;
}

// in: [S][K][N] f32  ->  out: [S][N][K] bf16   (K, N multiples of 32)
__global__ void transpose_cvt(const float* __restrict__ in,
                              unsigned short* __restrict__ out,
                              int K, int N) {
    __shared__ unsigned short sh[32][33];
    const int s  = blockIdx.z;
    const int k0 = blockIdx.x * 32;
    const int n0 = blockIdx.y * 32;
    const int tx = threadIdx.x & 31;
    const int ty = threadIdx.x >> 5;   // 0..7
    const float* ip = in + (size_t)s * K * N;
    unsigned short* op = out + (size_t)s * N * K;
#pragma unroll
    for (int i = 0; i < 4; ++i) {
        int k = ty + 8 * i;
        sh[tx][k] = f2bf(ip[(size_t)(k0 + k) * N + n0 + tx]);
    }
    __syncthreads();
#pragma unroll
    for (int i = 0; i < 4; ++i) {
        int n = ty + 8 * i;
        op[(size_t)(n0 + n) * K + k0 + tx] = sh[n][tx];
    }
}

// C = silu(A @ Wt^T + bias), written as bf16.
// A: [S][APS][K]  (f32 if AF32 else bf16, row-major, K-contiguous)
// Wt: [S][256][K] bf16 (K-contiguous)
// Out: [S*APS][256] bf16
// Block: 256 thr = 4 waves. Tile M=64, N=256 (full), BK=32.
// Wave w covers n in [w*64, w*64+64); 4x4 frags of 16x16x32 MFMA.
template <bool AF32>
__global__ __launch_bounds__(256, 2) void mlp_gemm(
    const void* __restrict__ Ag,
    const unsigned short* __restrict__ Wt,
    const float* __restrict__ bias,
    unsigned short* __restrict__ Out,
    int K) {
    // A tile: 64 rows x 32 k, padded to 48 bf16/row (96 B: 16B-aligned b128, uniform banks)
    __shared__ unsigned short Asm[64 * 48];
    // B tile: 256 rows (n) x 32 k, unpadded (required by global_load_lds lane order)
    __shared__ unsigned short Bsm[256 * 32];

    const int tid  = threadIdx.x;
    const int w    = tid >> 6;
    const int lane = tid & 63;
    const int s    = blockIdx.y;
    const int m0   = blockIdx.x * 64;

    const unsigned short* Wts = Wt + (size_t)s * 256 * K;
    const int brow = lane >> 2;          // row-within-16 for glds
    const int bkin = (lane & 3) * 8;     // k element offset for glds
    const int lm   = lane & 15;
    const int kgl  = (lane >> 4) * 8;    // frag k offset (elements)
    constexpr int ASTRIDE = AF32 ? 48 : 32;

    f32x4 acc[4][4];
#pragma unroll
    for (int i = 0; i < 4; ++i)
#pragma unroll
        for (int j = 0; j < 4; ++j)
#pragma unroll
            for (int e = 0; e < 4; ++e) acc[i][j][e] = 0.0f;

    for (int k0 = 0; k0 < K; k0 += 32) {
        __syncthreads();   // previous iter's frags consumed before overwrite

        // ---- B stage: 16 KB via global_load_lds dwordx4 (4 insts/thread) ----
#pragma unroll
        for (int j = 0; j < 4; ++j) {
            const unsigned short* gp =
                Wts + (size_t)(16 * (4 * w + j) + brow) * K + k0 + bkin;
            __builtin_amdgcn_global_load_lds((gptr_t)gp,
                                             (lptr_t)&Bsm[(4 * w + j) * 512],
                                             16, 0, 0);
        }

        // ---- A stage ----
        if constexpr (AF32) {
            const float* Af = (const float*)Ag + ((size_t)s * APS + m0) * K;
#pragma unroll
            for (int r = 0; r < 2; ++r) {
                int f   = tid + 256 * r;     // float4 index in 64x32 tile
                int row = f >> 3;
                int c4  = f & 7;
                float4 v = *(const float4*)(Af + (size_t)row * K + k0 + c4 * 4);
                ushort4 b;
                b.x = f2bf(v.x); b.y = f2bf(v.y); b.z = f2bf(v.z); b.w = f2bf(v.w);
                *(ushort4*)(&Asm[row * 48 + c4 * 4]) = b;
            }
        } else {
            const unsigned short* Ab =
                (const unsigned short*)Ag + ((size_t)s * APS + m0) * K;
            const unsigned short* gp = Ab + (size_t)(16 * w + brow) * K + k0 + bkin;
            __builtin_amdgcn_global_load_lds((gptr_t)gp, (lptr_t)&Asm[w * 512],
                                             16, 0, 0);
        }

        __syncthreads();   // drains vmcnt (glds) + lgkmcnt (ds_write)

        // ---- fragments + MFMA ----
        bf16x8 af[4], bf[4];
#pragma unroll
        for (int mf = 0; mf < 4; ++mf)
            af[mf] = *(const bf16x8*)(&Asm[(mf * 16 + lm) * ASTRIDE + kgl]);
#pragma unroll
        for (int nf = 0; nf < 4; ++nf)
            bf[nf] = *(const bf16x8*)(&Bsm[(w * 64 + nf * 16 + lm) * 32 + kgl]);
#pragma unroll
        for (int mf = 0; mf < 4; ++mf)
#pragma unroll
            for (int nf = 0; nf < 4; ++nf)
                acc[mf][nf] = __builtin_amdgcn_mfma_f32_16x16x32_bf16(
                    af[mf], bf[nf], acc[mf][nf], 0, 0, 0);
    }

    // ---- epilogue: bias + SiLU + bf16 store ----
    // C/D layout: col = lane&15 (n), row = (lane>>4)*4 + reg (m)
    unsigned short* op = Out + ((size_t)s * APS + m0) * 256;
    const float* bp = bias + s * 256;
    const int q = lane >> 4;
#pragma unroll
    for (int nf = 0; nf < 4; ++nf) {
        int col  = w * 64 + nf * 16 + lm;
        float bv = bp[col];
#pragma unroll
        for (int mf = 0; mf < 4; ++mf)
#pragma unroll
            for (int i = 0; i < 4; ++i) {
                int row = mf * 16 + q * 4 + i;
                float x = acc[mf][nf][i] + bv;
                float y = x / (1.0f + __expf(-x));
                op[(size_t)row * 256 + col] = f2bf(y);
            }
    }
}

// e[a] = dot(h3[a], W4[s]) + b4[s]; atomicAdd into per-structure bins.
__global__ void final_reduce(const unsigned short* __restrict__ H3,
                             const float* __restrict__ W4,
                             const float* __restrict__ b4,
                             const int* __restrict__ sidx,
                             float* __restrict__ out) {
    const int atom = blockIdx.x * 4 + (threadIdx.x >> 6);
    const int lane = threadIdx.x & 63;
    const int s    = atom >> 13;   // APS = 8192
    ushort4 hv = *(const ushort4*)(H3 + (size_t)atom * 256 + lane * 4);
    float4  wv = *(const float4*)(W4 + s * 256 + lane * 4);
    float sum = bf2f(hv.x) * wv.x + bf2f(hv.y) * wv.y +
                bf2f(hv.z) * wv.z + bf2f(hv.w) * wv.w;
#pragma unroll
    for (int off = 32; off > 0; off >>= 1) sum += __shfl_down(sum, off, 64);
    if (lane == 0) atomicAdd(&out[sidx[atom]], sum + b4[s]);
}

extern "C" void kernel_launch(void* const* d_in, const int* in_sizes, int n_in,
                              void* d_out, int out_size, void* d_ws, size_t ws_size,
                              hipStream_t stream) {
    const float* features = (const float*)d_in[0];
    const int*   sidx     = (const int*)d_in[1];
    // d_in[2] = n_structures scalar (== N_STRUCT)
    const float* W1 = (const float*)d_in[3];
    const float* b1 = (const float*)d_in[4];
    const float* W2 = (const float*)d_in[5];
    const float* b2 = (const float*)d_in[6];
    const float* W3 = (const float*)d_in[7];
    const float* b3 = (const float*)d_in[8];
    const float* W4 = (const float*)d_in[9];
    const float* b4 = (const float*)d_in[10];
    float* out = (float*)d_out;

    char* ws = (char*)d_ws;
    unsigned short* Wt1 = (unsigned short*)ws; ws += (size_t)N_SPECIES * HIDDEN * N_FEAT * 2;
    unsigned short* Wt2 = (unsigned short*)ws; ws += (size_t)N_SPECIES * HIDDEN * HIDDEN * 2;
    unsigned short* Wt3 = (unsigned short*)ws; ws += (size_t)N_SPECIES * HIDDEN * HIDDEN * 2;
    unsigned short* H1  = (unsigned short*)ws; ws += (size_t)N_ATOMS * HIDDEN * 2;
    unsigned short* H2  = (unsigned short*)ws; ws += (size_t)N_ATOMS * HIDDEN * 2;
    unsigned short* H3  = H1;   // layer-3 output reuses H1's buffer

    hipMemsetAsync(d_out, 0, N_STRUCT * sizeof(float), stream);

    transpose_cvt<<<dim3(N_FEAT / 32, HIDDEN / 32, N_SPECIES), 256, 0, stream>>>(W1, Wt1, N_FEAT, HIDDEN);
    transpose_cvt<<<dim3(HIDDEN / 32, HIDDEN / 32, N_SPECIES), 256, 0, stream>>>(W2, Wt2, HIDDEN, HIDDEN);
    transpose_cvt<<<dim3(HIDDEN / 32, HIDDEN / 32, N_SPECIES), 256, 0, stream>>>(W3, Wt3, HIDDEN, HIDDEN);

    mlp_gemm<true><<<dim3(APS / 64, N_SPECIES), 256, 0, stream>>>(features, Wt1, b1, H1, N_FEAT);
    mlp_gemm<false><<<dim3(APS / 64, N_SPECIES), 256, 0, stream>>>(H1, Wt2, b2, H2, HIDDEN);
    mlp_gemm<false><<<dim3(APS / 64, N_SPECIES), 256, 0, stream>>>(H2, Wt3, b3, H3, HIDDEN);

    final_reduce<<<N_ATOMS / 4, 256, 0, stream>>>(H3, W4, b4, sidx, out);
}

// Round 2
// 1439.985 us; speedup vs baseline: 1.0101x; 1.0101x over previous
//
#include <hip/hip_runtime.h>
#include <hip/hip_bf16.h>

#define N_ATOMS   32768
#define N_SPECIES 4
#define N_FEAT    7584
#define HIDDEN    256
#define N_STRUCT  1024
#define APS       8192   // atoms per species

typedef __attribute__((ext_vector_type(8))) short bf16x8;
typedef __attribute__((ext_vector_type(4))) float f32x4;

typedef const __attribute__((address_space(1))) void* gptr_t;
typedef __attribute__((address_space(3))) void* lptr_t;

__device__ __forceinline__ unsigned short f2bf(float x) {
    union { float f; unsigned u; } v; v.f = x;
    unsigned r = v.u + 0x7FFFu + ((v.u >> 16) & 1u);   // RNE
    return (unsigned short)(r >> 16);
}
__device__ __forceinline__ float bf2f(unsigned short h) {
    union { unsigned u; float f; } v; v.u = ((unsigned)h) << 16;
    return v.f;
}

// in: [S][K][N] f32  ->  out: [S][N][K] bf16   (K, N multiples of 32)
__global__ void transpose_cvt(const float* __restrict__ in,
                              unsigned short* __restrict__ out,
                              int K, int N) {
    __shared__ unsigned short sh[32][33];
    const int s  = blockIdx.z;
    const int k0 = blockIdx.x * 32;
    const int n0 = blockIdx.y * 32;
    const int tx = threadIdx.x & 31;
    const int ty = threadIdx.x >> 5;   // 0..7
    const float* ip = in + (size_t)s * K * N;
    unsigned short* op = out + (size_t)s * N * K;
#pragma unroll
    for (int i = 0; i < 4; ++i) {
        int k = ty + 8 * i;
        sh[tx][k] = f2bf(ip[(size_t)(k0 + k) * N + n0 + tx]);
    }
    __syncthreads();
#pragma unroll
    for (int i = 0; i < 4; ++i) {
        int n = ty + 8 * i;
        op[(size_t)(n0 + n) * K + k0 + tx] = sh[n][tx];
    }
}

// ---------------------------------------------------------------------------
// Fused 4-layer MLP + scatter. One block = 64 atoms of one species, full
// hidden width 256. 256 threads = 4 waves; wave w owns n in [64w, 64w+64).
// Single-barrier double-buffered K-loop: barrier -> prefetch(next) ->
// frag reads + MFMA (cur) -> commit A(next). H stays in LDS across layers.
// ---------------------------------------------------------------------------

// B stage: 16 KB tile [256 n-rows][32 k] via global_load_lds dwordx4.
// Lane l of wave w, inst j covers row 16*(4w+j)+(l>>2), k-chunk (l&3)*8 —
// lds dest = wave-uniform base + l*16B (required glds layout, HW-verified R1).
__device__ __forceinline__ void stage_B(const unsigned short* __restrict__ Wts,
                                        int K, int k0,
                                        unsigned short* BsmBuf, int w, int lane) {
#pragma unroll
    for (int j = 0; j < 4; ++j) {
        const unsigned short* gp =
            Wts + (size_t)(16 * (4 * w + j) + (lane >> 2)) * K + k0 + (lane & 3) * 8;
        __builtin_amdgcn_global_load_lds((gptr_t)gp,
                                         (lptr_t)&BsmBuf[(4 * w + j) * 512],
                                         16, 0, 0);
    }
}

__device__ __forceinline__ void load_A(const float* __restrict__ Af, int K, int k0,
                                       int tid, float4 v[2]) {
#pragma unroll
    for (int r = 0; r < 2; ++r) {
        int f = tid + 256 * r;          // float4 index in 64x32 tile
        int row = f >> 3, c4 = f & 7;
        v[r] = *(const float4*)(Af + (size_t)row * K + k0 + c4 * 4);
    }
}
__device__ __forceinline__ void commit_A(unsigned short* AsmBuf, int tid,
                                         const float4 v[2]) {
#pragma unroll
    for (int r = 0; r < 2; ++r) {
        int f = tid + 256 * r;
        int row = f >> 3, c4 = f & 7;
        ushort4 b;
        b.x = f2bf(v[r].x); b.y = f2bf(v[r].y);
        b.z = f2bf(v[r].z); b.w = f2bf(v[r].w);
        *(ushort4*)(&AsmBuf[row * 48 + c4 * 4]) = b;
    }
}

#define HPAD 264   // H-tile stride: 264*2B = 528B = 132 dw -> bank step 4/row, 2-way (free)

__global__ __launch_bounds__(256, 2) void fused_mlp(
    const float* __restrict__ features,
    const unsigned short* __restrict__ Wt1,   // [S][256][N_FEAT] bf16
    const float* __restrict__ b1,
    const unsigned short* __restrict__ Wt2,   // [S][256][256] bf16
    const float* __restrict__ b2,
    const unsigned short* __restrict__ Wt3,
    const float* __restrict__ b3,
    const float* __restrict__ W4,             // [S][256] f32
    const float* __restrict__ b4,
    const int* __restrict__ sidx,
    float* __restrict__ out) {
    __shared__ unsigned short Asm[2][64 * 48];    // layer-1 fp32->bf16 staging
    __shared__ unsigned short Bsm[2][256 * 32];
    __shared__ unsigned short Hsm[64 * HPAD];     // live H tile across layers

    const int tid  = threadIdx.x;
    const int w    = tid >> 6;
    const int lane = tid & 63;
    const int lm   = lane & 15;
    const int q    = lane >> 4;
    const int kgl  = q * 8;
    const int s    = blockIdx.x >> 7;             // 128 blocks per species
    const int m0   = (blockIdx.x & 127) * 64;

    f32x4 acc[4][4];

    // ======================= Layer 1: A fp32 global, K=N_FEAT ================
    {
        const float* Af = features + ((size_t)s * APS + m0) * N_FEAT;
        const unsigned short* Wts = Wt1 + (size_t)s * 256 * N_FEAT;
#pragma unroll
        for (int i = 0; i < 4; ++i)
#pragma unroll
            for (int j = 0; j < 4; ++j)
#pragma unroll
                for (int e = 0; e < 4; ++e) acc[i][j][e] = 0.0f;

        float4 av[2];
        stage_B(Wts, N_FEAT, 0, Bsm[0], w, lane);
        load_A(Af, N_FEAT, 0, tid, av);
        commit_A(Asm[0], tid, av);

        int buf = 0;
        for (int k0 = 0; k0 < N_FEAT; k0 += 32, buf ^= 1) {
            __syncthreads();   // drains prev glds (vmcnt) + ds_writes (lgkm)
            const bool more = (k0 + 32 < N_FEAT);
            if (more) {
                stage_B(Wts, N_FEAT, k0 + 32, Bsm[buf ^ 1], w, lane);
                load_A(Af, N_FEAT, k0 + 32, tid, av);
            }
            bf16x8 af[4], bfr[4];
#pragma unroll
            for (int mf = 0; mf < 4; ++mf)
                af[mf] = *(const bf16x8*)(&Asm[buf][(mf * 16 + lm) * 48 + kgl]);
#pragma unroll
            for (int nf = 0; nf < 4; ++nf)
                bfr[nf] = *(const bf16x8*)(&Bsm[buf][(w * 64 + nf * 16 + lm) * 32 + kgl]);
#pragma unroll
            for (int mf = 0; mf < 4; ++mf)
#pragma unroll
                for (int nf = 0; nf < 4; ++nf)
                    acc[mf][nf] = __builtin_amdgcn_mfma_f32_16x16x32_bf16(
                        af[mf], bfr[nf], acc[mf][nf], 0, 0, 0);
            if (more) commit_A(Asm[buf ^ 1], tid, av);
        }
        __syncthreads();   // all frag reads done before Hsm epilogue
        const float* bp = b1 + s * 256;
#pragma unroll
        for (int nf = 0; nf < 4; ++nf) {
            int col = w * 64 + nf * 16 + lm;
            float bv = bp[col];
#pragma unroll
            for (int mf = 0; mf < 4; ++mf)
#pragma unroll
                for (int i = 0; i < 4; ++i) {
                    int row = mf * 16 + q * 4 + i;
                    float x = acc[mf][nf][i] + bv;
                    Hsm[row * HPAD + col] = f2bf(x / (1.0f + __expf(-x)));
                }
        }
    }

    // =================== Layers 2,3: A from Hsm, K=256 =======================
#pragma unroll 1
    for (int layer = 0; layer < 2; ++layer) {
        const unsigned short* Wts =
            (layer == 0 ? Wt2 : Wt3) + (size_t)s * 256 * 256;
        const float* bp = (layer == 0 ? b2 : b3) + s * 256;
#pragma unroll
        for (int i = 0; i < 4; ++i)
#pragma unroll
            for (int j = 0; j < 4; ++j)
#pragma unroll
                for (int e = 0; e < 4; ++e) acc[i][j][e] = 0.0f;

        stage_B(Wts, 256, 0, Bsm[0], w, lane);
        int buf = 0;
        for (int k0 = 0; k0 < 256; k0 += 32, buf ^= 1) {
            __syncthreads();   // glds drained; Hsm epilogue writes visible
            if (k0 + 32 < 256)
                stage_B(Wts, 256, k0 + 32, Bsm[buf ^ 1], w, lane);
            bf16x8 af[4], bfr[4];
#pragma unroll
            for (int mf = 0; mf < 4; ++mf)
                af[mf] = *(const bf16x8*)(&Hsm[(mf * 16 + lm) * HPAD + k0 + kgl]);
#pragma unroll
            for (int nf = 0; nf < 4; ++nf)
                bfr[nf] = *(const bf16x8*)(&Bsm[buf][(w * 64 + nf * 16 + lm) * 32 + kgl]);
#pragma unroll
            for (int mf = 0; mf < 4; ++mf)
#pragma unroll
                for (int nf = 0; nf < 4; ++nf)
                    acc[mf][nf] = __builtin_amdgcn_mfma_f32_16x16x32_bf16(
                        af[mf], bfr[nf], acc[mf][nf], 0, 0, 0);
        }
        __syncthreads();   // all Hsm reads (as A) done before overwrite
#pragma unroll
        for (int nf = 0; nf < 4; ++nf) {
            int col = w * 64 + nf * 16 + lm;
            float bv = bp[col];
#pragma unroll
            for (int mf = 0; mf < 4; ++mf)
#pragma unroll
                for (int i = 0; i < 4; ++i) {
                    int row = mf * 16 + q * 4 + i;
                    float x = acc[mf][nf][i] + bv;
                    Hsm[row * HPAD + col] = f2bf(x / (1.0f + __expf(-x)));
                }
        }
    }

    // ============ Layer 4: e[a] = dot(h3[a], W4[s]) + b4[s]; scatter =========
    __syncthreads();
    {
        const float* W4s = W4 + s * 256;
        const int a_loc = w * 16 + lm;    // 0..63
        float sum = 0.0f;
#pragma unroll
        for (int j8 = 0; j8 < 8; ++j8) {
            bf16x8 hv = *(const bf16x8*)(&Hsm[a_loc * HPAD + q * 64 + j8 * 8]);
            float4 w0 = *(const float4*)(W4s + q * 64 + j8 * 8);
            float4 w1 = *(const float4*)(W4s + q * 64 + j8 * 8 + 4);
            sum += bf2f((unsigned short)hv[0]) * w0.x + bf2f((unsigned short)hv[1]) * w0.y +
                   bf2f((unsigned short)hv[2]) * w0.z + bf2f((unsigned short)hv[3]) * w0.w +
                   bf2f((unsigned short)hv[4]) * w1.x + bf2f((unsigned short)hv[5]) * w1.y +
                   bf2f((unsigned short)hv[6]) * w1.z + bf2f((unsigned short)hv[7]) * w1.w;
        }
        sum += __shfl_xor(sum, 16, 64);
        sum += __shfl_xor(sum, 32, 64);
        if (q == 0) {
            int atom = s * APS + m0 + a_loc;
            atomicAdd(&out[sidx[atom]], sum + b4[s]);
        }
    }
}

extern "C" void kernel_launch(void* const* d_in, const int* in_sizes, int n_in,
                              void* d_out, int out_size, void* d_ws, size_t ws_size,
                              hipStream_t stream) {
    const float* features = (const float*)d_in[0];
    const int*   sidx     = (const int*)d_in[1];
    // d_in[2] = n_structures scalar (== N_STRUCT)
    const float* W1 = (const float*)d_in[3];
    const float* b1 = (const float*)d_in[4];
    const float* W2 = (const float*)d_in[5];
    const float* b2 = (const float*)d_in[6];
    const float* W3 = (const float*)d_in[7];
    const float* b3 = (const float*)d_in[8];
    const float* W4 = (const float*)d_in[9];
    const float* b4 = (const float*)d_in[10];
    float* out = (float*)d_out;

    char* ws = (char*)d_ws;
    unsigned short* Wt1 = (unsigned short*)ws; ws += (size_t)N_SPECIES * HIDDEN * N_FEAT * 2;
    unsigned short* Wt2 = (unsigned short*)ws; ws += (size_t)N_SPECIES * HIDDEN * HIDDEN * 2;
    unsigned short* Wt3 = (unsigned short*)ws; ws += (size_t)N_SPECIES * HIDDEN * HIDDEN * 2;

    hipMemsetAsync(d_out, 0, N_STRUCT * sizeof(float), stream);

    transpose_cvt<<<dim3(N_FEAT / 32, HIDDEN / 32, N_SPECIES), 256, 0, stream>>>(W1, Wt1, N_FEAT, HIDDEN);
    transpose_cvt<<<dim3(HIDDEN / 32, HIDDEN / 32, N_SPECIES), 256, 0, stream>>>(W2, Wt2, HIDDEN, HIDDEN);
    transpose_cvt<<<dim3(HIDDEN / 32, HIDDEN / 32, N_SPECIES), 256, 0, stream>>>(W3, Wt3, HIDDEN, HIDDEN);

    fused_mlp<<<dim3(N_ATOMS / 64), 256, 0, stream>>>(
        features, Wt1, b1, Wt2, b2, Wt3, b3, W4, b4, sidx, out);
}